// Round 5
// baseline (16.782 us; speedup 1.0000x reference)
//
#include <hip/hip_runtime.h>
#include <stdint.h>

#define BATCH 2048
#define NPS 8
#define DFEAT 256

// Constant-address-space float: forces s_load (SMEM) codegen for uniform reads.
typedef const float __attribute__((address_space(4))) cfp;

// Block: 512 threads = 8 waves, handles 8 walkers x 1 spin (64 rows, 64 dets).
// Wave wq owns f-chunk [wq*32, wq*32+32) -> W reads are wave-uniform scalar
// loads (addrspace(4) guarantees s_load + v_fmac v,s,v inner loop).
// Lane (0..63) = one x-row; 16 accumulators (8 k of A = x_i.W1, 8 k of Bt = x_j.W2).
__global__ __launch_bounds__(512) void ppdet_kernel(
    const float* __restrict__ eq,      // (B, 16, 256)
    const float* __restrict__ r_ei,    // (B, 16, 4, 3)
    const float* __restrict__ W,       // (2, 512, 8)
    const float* __restrict__ bias,    // (2, 8)
    const float* __restrict__ env_dim, // (2, 8, 4, 3, 3)
    const float* __restrict__ env_ion, // (2, 4, 8)
    float* __restrict__ out)           // (2, 2048, 8)
{
    __shared__ __align__(16) float part[8 * 64 * 16]; // 32 KB, XOR-swizzled slots
    __shared__ __align__(16) float AB[64 * 16];       // [row][k<8:A+bias, k>=8:Bt]
    __shared__ __align__(16) float envl[512];         // [w][j][k]

    const int tid = threadIdx.x;
    const int bid = blockIdx.x;
    const int s  = bid & 1;
    const int b0 = (bid >> 1) * 8;

    const int wq   = __builtin_amdgcn_readfirstlane(tid >> 6); // 0..7, uniform
    const int lane = tid & 63;
    const int wl   = lane >> 3, ii = lane & 7;

    // This wave's 32 W1 rows (256 floats) / W2 at +2048, via SMEM pointer.
    cfp* wb1 = (cfp*)(uintptr_t)(W + s * 4096 + wq * 256);
    const size_t grow = (size_t)(b0 + wl) * 16 + s * 8 + ii;
    const float* xrow = eq + grow * DFEAT + wq * 32;

    float4 xv[8];
#pragma unroll
    for (int u = 0; u < 8; ++u) xv[u] = ((const float4*)xrow)[u];

    float acc[16];
#pragma unroll
    for (int k = 0; k < 16; ++k) acc[k] = 0.f;

#pragma unroll
    for (int u = 0; u < 8; ++u) {
        cfp* wr = wb1 + u * 32;
        float xs0 = xv[u].x, xs1 = xv[u].y, xs2 = xv[u].z, xs3 = xv[u].w;
#pragma unroll
        for (int c = 0; c < 4; ++c) {
            float xc = (c == 0) ? xs0 : (c == 1) ? xs1 : (c == 2) ? xs2 : xs3;
#pragma unroll
            for (int k = 0; k < 8; ++k) {
                acc[k]     = fmaf(xc, wr[c * 8 + k],        acc[k]);
                acc[8 + k] = fmaf(xc, wr[2048 + c * 8 + k], acc[8 + k]);
            }
        }
    }

    // Store partials; swizzled 4-float slot keeps b128 writes at the 8-way floor.
    {
        float* pb = part + (wq * 64 + lane) * 16;
        const int sw = (lane >> 1) & 3;
#pragma unroll
        for (int kg = 0; kg < 4; ++kg) {
            int slot = kg ^ sw;
            float4 v = make_float4(acc[kg * 4], acc[kg * 4 + 1],
                                   acc[kg * 4 + 2], acc[kg * 4 + 3]);
            *(float4*)(pb + slot * 4) = v;
        }
    }

    // Envelope: task = (w, k, j), j fastest so 8 lanes share (k,a) tables.
    {
        const int w = tid >> 6, k = (tid >> 3) & 7, j = tid & 7;
        const size_t rrow = ((size_t)(b0 + w) * 16 + s * 8 + j) * 12;
        const float4* rp = (const float4*)(r_ei + rrow);
        float4 ra = rp[0], rb = rp[1], rc = rp[2];
        float rr[12] = {ra.x, ra.y, ra.z, ra.w, rb.x, rb.y, rb.z, rb.w,
                        rc.x, rc.y, rc.z, rc.w};
        float e = 0.f;
#pragma unroll
        for (int a = 0; a < 4; ++a) {
            const float* Md = env_dim + ((size_t)(s * 8 + k) * 4 + a) * 9;
            float r0 = rr[a * 3], r1 = rr[a * 3 + 1], r2 = rr[a * 3 + 2];
            float e0 = r0 * Md[0] + r1 * Md[3] + r2 * Md[6];
            float e1 = r0 * Md[1] + r1 * Md[4] + r2 * Md[7];
            float e2 = r0 * Md[2] + r1 * Md[5] + r2 * Md[8];
            float dist = sqrtf(e0 * e0 + e1 * e1 + e2 * e2);
            e = fmaf(env_ion[(s * 4 + a) * 8 + k], __expf(-dist), e);
        }
        envl[w * 64 + j * 8 + k] = e;
    }

    __syncthreads();

    // Reduce 8 f-chunk partials -> AB (swizzle-aware), fold bias into A half.
    if (tid < 256) {
        const int row = tid >> 2, sl = tid & 3;
        const int g = sl ^ ((row >> 1) & 3); // true k-group held in slot sl
        float4 sum = make_float4(0.f, 0.f, 0.f, 0.f);
#pragma unroll
        for (int q2 = 0; q2 < 8; ++q2) {
            float4 v = *(const float4*)(part + (q2 * 64 + row) * 16 + sl * 4);
            sum.x += v.x; sum.y += v.y; sum.z += v.z; sum.w += v.w;
        }
        if (g < 2) {
            sum.x += bias[s * 8 + g * 4];
            sum.y += bias[s * 8 + g * 4 + 1];
            sum.z += bias[s * 8 + g * 4 + 2];
            sum.w += bias[s * 8 + g * 4 + 3];
        }
        *(float4*)(AB + row * 16 + g * 4) = sum;
    }

    __syncthreads();

    // One 8x8 determinant per thread (64 dets/block), in-register LU with
    // partial pivoting; all register indices compile-time constants.
    if (tid < 64) {
        const int w = tid >> 3, i = tid & 7;
        float Arow[8];
#pragma unroll
        for (int k = 0; k < 8; ++k) Arow[k] = AB[(w * 8 + i) * 16 + k];
        float M[8][8];
#pragma unroll
        for (int j = 0; j < 8; ++j) {
#pragma unroll
            for (int k = 0; k < 8; ++k)
                M[j][k] = (Arow[k] + AB[(w * 8 + j) * 16 + 8 + k])
                          * envl[w * 64 + j * 8 + k];
        }
        float det = 1.f;
#pragma unroll
        for (int p = 0; p < 8; ++p) {
            int piv = p;
            float mx = fabsf(M[p][p]);
#pragma unroll
            for (int r2 = p + 1; r2 < 8; ++r2) {
                float v = fabsf(M[r2][p]);
                if (v > mx) { mx = v; piv = r2; }
            }
#pragma unroll
            for (int r2 = p + 1; r2 < 8; ++r2) {
                bool sw = (piv == r2);
#pragma unroll
                for (int c = p; c < 8; ++c) {
                    float a = M[p][c], bb = M[r2][c];
                    M[p][c]  = sw ? bb : a;
                    M[r2][c] = sw ? a : bb;
                }
            }
            det = (piv != p) ? -det : det;
            float d = M[p][p];
            det *= d;
            float inv = (d != 0.f) ? 1.f / d : 0.f;
#pragma unroll
            for (int r2 = p + 1; r2 < 8; ++r2) {
                float fct = M[r2][p] * inv;
#pragma unroll
                for (int c = p + 1; c < 8; ++c) M[r2][c] -= fct * M[p][c];
            }
        }
        out[(size_t)s * (BATCH * NPS) + (size_t)(b0 + w) * NPS + i] = det;
    }
}

extern "C" void kernel_launch(void* const* d_in, const int* in_sizes, int n_in,
                              void* d_out, int out_size, void* d_ws, size_t ws_size,
                              hipStream_t stream) {
    const float* eq      = (const float*)d_in[0];
    const float* r_ei    = (const float*)d_in[1];
    const float* W       = (const float*)d_in[2];
    const float* bias    = (const float*)d_in[3];
    const float* env_dim = (const float*)d_in[4];
    const float* env_ion = (const float*)d_in[5];
    float* out = (float*)d_out;

    ppdet_kernel<<<512, 512, 0, stream>>>(eq, r_ei, W, bias, env_dim, env_ion, out);
}